// Round 1
// baseline (741.893 us; speedup 1.0000x reference)
//
#include <hip/hip_runtime.h>

// ---------------------------------------------------------------------------
// e3nn-style tensor product:  X irreps 64x(l=0,1,2)  (x)  Y irreps 1x(l=0,1,2)
// 19 output paths, per-row out dim 5184, N=32768 rows.
// Memory-bound (679 MB write + 77 MB read -> ~125 us floor at 6.3 TB/s).
// ---------------------------------------------------------------------------

#define NP 19

constexpr int P_L1[NP]  = {0,0,0, 1,1,1,1,1,1,1, 2,2,2,2,2,2,2,2,2};
constexpr int P_L2[NP]  = {0,1,2, 0,1,1,1,2,2,2, 0,1,1,1,2,2,2,2,2};
constexpr int P_L3[NP]  = {0,1,2, 1,0,1,2,1,2,3, 2,1,2,3,0,1,2,3,4};
// dense w3j table offsets (sizes d1*d2*d3, prefix sums; total 1225 floats)
constexpr int P_WOFF[NP] = {0,1,10,35,44,53,80,125,170,245,350,375,420,495,600,625,700,825,1000};
// output chunk offsets within a row (chunk size 64*d3; total 5184)
constexpr int P_ZOFF[NP] = {0,64,256,576,768,832,1024,1344,1536,1856,2304,2624,2816,3136,3584,3648,3840,4160,4608};
constexpr int WTOT = 1225;
constexpr int XD = 576, YD = 9, ZD = 5184;

// ------------------------- W3J init (mirrors the Python reference) ---------

__device__ inline double dfact(int n){ double r=1.0; for(int i=2;i<=n;++i) r*=(double)i; return r; }

// Condon-Shortley CG <j1 m1 j2 m2 | j3 m3> (Racah) -- exact mirror of _cg()
__device__ double cgc(int j1,int m1,int j2,int m2,int j3,int m3){
  if (m1+m2 != m3) return 0.0;
  double pre = (double)(2*j3+1) * dfact(j3+j1-j2)*dfact(j3-j1+j2)*dfact(j1+j2-j3)/dfact(j1+j2+j3+1);
  pre *= dfact(j3+m3)*dfact(j3-m3)*dfact(j1-m1)*dfact(j1+m1)*dfact(j2-m2)*dfact(j2+m2);
  double s = 0.0;
  for (int k=0;k<=j1+j2-j3;++k){
    int d0=j1+j2-j3-k, d1=j1-m1-k, d2=j2+m2-k, d3=j3-j2+m1+k, d4=j3-j1-m2+k;
    if (d0<0||d1<0||d2<0||d3<0||d4<0) continue;
    double t = 1.0/(dfact(k)*dfact(d0)*dfact(d1)*dfact(d2)*dfact(d3)*dfact(d4));
    s += (k&1) ? -t : t;
  }
  return sqrt(pre)*s;
}

// complex->real SH change of basis Q(l)[r][c] -- exact mirror of _Q()
__device__ inline void Qv(int l,int r,int c,double& re,double& im){
  re=0.0; im=0.0;
  const double s2 = 0.70710678118654752440;
  if (r==l){ if (c==l) re=1.0; return; }
  if (r>l){ int m=r-l;
    if (c==l-m)      re = s2;
    else if (c==l+m) re = (m&1)? -s2 : s2;     // (-1)^m * s2
  } else { int m=l-r;
    if (c==l-m)      im = s2;                  // i*s2
    else if (c==l+m) im = (m&1)? s2 : -s2;     // -i*(-1)^m*s2
  }
}

// one block per path; fp64; writes alpha-scaled real-basis w3j (float) to ws
__global__ void w3j_init(float* __restrict__ w){
  const int p = blockIdx.x;
  const int l1=P_L1[p], l2=P_L2[p], l3=P_L3[p];
  const int d1=2*l1+1, d2=2*l2+1, d3=2*l3+1;
  __shared__ double Cre[25];     // complex-basis 3j (real-valued), [a*d2+b], m3 implied
  __shared__ double Tre[225];
  __shared__ double Tim[225];
  __shared__ int pick;
  const int t = threadIdx.x;

  if (t < d1*d2){
    int a=t/d2, b=t%d2;
    int m1=a-l1, m2=b-l2, m3=-(m1+m2);
    int am3 = m3<0 ? -m3 : m3;
    double v = 0.0;
    if (am3 <= l3){
      v = cgc(l1,m1,l2,m2,l3,-m3) / sqrt((double)(2*l3+1));
      if ((l1-l2-m3)&1) v = -v;                // (-1)^(l1-l2-m3)
    }
    Cre[t] = v;
  }
  __syncthreads();

  const int ne = d1*d2*d3;
  for (int e=t; e<ne; e+=blockDim.x){
    int i = e/(d2*d3); int r = e%(d2*d3); int j = r/d3; int k = r%d3;
    double tre=0.0, tim=0.0;
    for (int a=0;a<d1;a++){
      for (int b=0;b<d2;b++){
        double cr = Cre[a*d2+b];
        if (cr == 0.0) continue;
        int m3 = -((a-l1)+(b-l2));
        int c = m3 + l3;
        if (c < 0 || c >= d3) continue;
        double q1r,q1i,q2r,q2i,q3r,q3i;
        Qv(l1,i,a,q1r,q1i);
        Qv(l2,j,b,q2r,q2i);
        Qv(l3,k,c,q3r,q3i);
        double pr = q1r*q2r - q1i*q2i;
        double pi = q1r*q2i + q1i*q2r;
        double rr = pr*q3r - pi*q3i;
        double ri = pr*q3i + pi*q3r;
        tre += rr*cr; tim += ri*cr;
      }
    }
    Tre[e]=tre; Tim[e]=tim;
  }
  __syncthreads();

  if (t==0){
    double sre=0.0, sim=0.0;
    for (int e=0;e<ne;e++){ sre += fabs(Tre[e]); sim += fabs(Tim[e]); }
    pick = (sre >= sim) ? 0 : 1;
  }
  __syncthreads();

  const double alpha = sqrt((double)(2*l3+1));  // component-norm factor, folded in
  for (int e=t; e<ne; e+=blockDim.x){
    double v = pick ? Tim[e] : Tre[e];
    w[P_WOFF[p]+e] = (float)(v*alpha);
  }
}

// ------------------------------ main kernel --------------------------------
// one wave per row; lane u = channel (mu=64 == wavefront size).
// w (1225 f32) staged once per block into LDS; all w/y reads are wave-uniform
// LDS broadcasts (conflict-free). Fully unrolled constexpr path table.

__global__ __launch_bounds__(256) void tp_main(const float* __restrict__ x,
                                               const float* __restrict__ y,
                                               const float* __restrict__ w,
                                               float* __restrict__ out,
                                               int nrow){
  __shared__ float ws[WTOT];
  for (int t=threadIdx.x; t<WTOT; t+=256) ws[t] = w[t];
  __syncthreads();

  const int u = threadIdx.x & 63;
  int row = blockIdx.x*4 + (threadIdx.x>>6);
  row = __builtin_amdgcn_readfirstlane(row);   // provably wave-uniform
  if (row >= nrow) return;

  const float* xr = x + (size_t)row*XD;
  const float* yr = y + (size_t)row*YD;
  float*       zr = out + (size_t)row*ZD;

  float yv[9];
  #pragma unroll
  for (int j=0;j<9;++j) yv[j] = yr[j];

  float xv0 = xr[u];          // l=0 block: x[n, u]
  float xv1[3];
  #pragma unroll
  for (int i=0;i<3;++i) xv1[i] = xr[64 + 3*u + i];   // l=1 block
  float xv2[5];
  #pragma unroll
  for (int i=0;i<5;++i) xv2[i] = xr[256 + 5*u + i];  // l=2 block

  #pragma unroll
  for (int p=0;p<NP;++p){
    const int l1=P_L1[p], l2=P_L2[p], l3=P_L3[p];
    const int d1=2*l1+1, d2=2*l2+1, d3=2*l3+1;
    const int yo = (l2==0) ? 0 : (l2==1 ? 1 : 4);

    float acc[9];
    #pragma unroll
    for (int k=0;k<d3;++k) acc[k] = 0.f;

    #pragma unroll
    for (int i=0;i<d1;++i){
      const float xi = (l1==0) ? xv0 : (l1==1 ? xv1[i] : xv2[i]);
      #pragma unroll
      for (int j=0;j<d2;++j){
        const float xy = xi * yv[yo+j];
        #pragma unroll
        for (int k=0;k<d3;++k)
          acc[k] += xy * ws[P_WOFF[p] + (i*d2+j)*d3 + k];
      }
    }

    float* zp = zr + P_ZOFF[p] + u*d3;   // chunk layout: u-major, k inner
    #pragma unroll
    for (int k=0;k<d3;++k) zp[k] = acc[k];
  }
}

// ------------------------------ launch -------------------------------------

extern "C" void kernel_launch(void* const* d_in, const int* in_sizes, int n_in,
                              void* d_out, int out_size, void* d_ws, size_t ws_size,
                              hipStream_t stream) {
  const float* x = (const float*)d_in[0];
  const float* y = (const float*)d_in[1];
  float* out = (float*)d_out;
  float* w   = (float*)d_ws;           // 1225 floats of scratch for w3j table
  const int nrow = in_sizes[0] / XD;   // 32768

  hipLaunchKernelGGL(w3j_init, dim3(NP), dim3(256), 0, stream, w);
  const int nb = (nrow + 3) / 4;       // 4 rows (4 waves) per block
  hipLaunchKernelGGL(tp_main, dim3(nb), dim3(256), 0, stream, x, y, w, out, nrow);
}